// Round 8
// baseline (77.900 us; speedup 1.0000x reference)
//
#include <hip/hip_runtime.h>
#include <math.h>

// FFM_69664369541798 — round 8: DIAGNOSTIC. ffm_final launched 4x (idempotent)
// to measure its true cost via the dur delta. Real changes kept for later:
// codes packed to one uint2/row (8B), GEMM blocks scheduled before compress.

constexpr int B_ROWS = 262144;
constexpr int NFEAT  = 45;

// ---- ws layout (float-element offsets) ----
constexpr int OFF_LWG  = 8;        // 2
constexpr int OFF_LWO  = 10;       // 21
constexpr int OFF_AG   = 31;       // 2
constexpr int OFF_AO   = 33;       // 21
constexpr int OFF_GO   = 54;       // 42 -> 96
constexpr int OFF_NO   = 96;       // 21*256 f32
constexpr int OFF_NF   = 5472;     // 2*256
constexpr int OFF_NA   = 5984;     // 256
constexpr int LDS_TAB  = 6240;
constexpr int OFF_PUOB = 6240;     // bf16 943*32
constexpr int OFF_PTOB = 21328;    // bf16 1682*32
constexpr int OFF_DMUB = 48240;    // bf16 943*32
constexpr int OFF_DMTB = 63328;    // bf16 1682*32
constexpr int OFF_UTB  = 90240;    // bf16 943*1682
constexpr int OFF_CODE = 883304;   // uint2 per row (8B)
constexpr size_t TOT_FLOATS = 883304 + (size_t)B_ROWS * 2;
constexpr size_t TOT_BYTES  = TOT_FLOATS * 4;

__device__ inline float dot64(const float* __restrict__ a, const float* __restrict__ b) {
    float s = 0.f;
    #pragma unroll
    for (int k = 0; k < 64; k += 4) {
        const float4 av = *reinterpret_cast<const float4*>(a + k);
        const float4 bv = *reinterpret_cast<const float4*>(b + k);
        s += av.x * bv.x + av.y * bv.y + av.z * bv.z + av.w * bv.w;
    }
    return s;
}
__device__ inline unsigned short f2b(float x) {
    union { float f; unsigned u; } v; v.f = x;
    return (unsigned short)((v.u + 0x7FFFu + ((v.u >> 16) & 1u)) >> 16);
}
__device__ inline float b2f(unsigned short u) {
    union { unsigned u; float f; } v; v.u = (unsigned)u << 16; return v.f;
}

// ka2 block order: [UT 405][consts 1][PUO 15][PTO 27][DMU 15][DMT 27][NOX 4][compress 1024]
constexpr int KA_PRE     = 405 + 1 + 15 + 27 + 15 + 27 + 4;   // 494
constexpr int KA2_BLOCKS = KA_PRE + 1024;                     // 1518

__global__ __launch_bounds__(256) void ka2_kernel(
    const float* __restrict__ fv,
    const float* __restrict__ AU, const float* __restrict__ AI,
    const float* __restrict__ GU, const float* __restrict__ GI,
    const float* __restrict__ OU, const float* __restrict__ OI,
    const float* __restrict__ MU, const float* __restrict__ MI,
    const float* __restrict__ UU, const float* __restrict__ UI,
    const float* __restrict__ TU, const float* __restrict__ TI,
    const float* __restrict__ user_w, const float* __restrict__ item_w,
    const float* __restrict__ lin_w, const float* __restrict__ lin_b,
    float* __restrict__ ws)
{
    __shared__ __align__(16) float shbuf[11520];
    const int tid = threadIdx.x;
    int b = blockIdx.x;

    if (b >= KA_PRE) {
        // ---- compress 256 rows -> one uint2 code per row ----
        const int cb = b - KA_PRE;
        const int lane = tid & 63, wid = tid >> 6;
        float* sf = shbuf + wid * 2880;
        const float* src = fv + (size_t)(cb * 256 + wid * 64) * NFEAT;
        #pragma unroll
        for (int i = 0; i < 11; ++i) {
            const int s4 = i * 64 + lane;
            *reinterpret_cast<float4*>(sf + s4 * 4) =
                *reinterpret_cast<const float4*>(src + s4 * 4);
        }
        sf[2816 + lane] = src[2816 + lane];     // wave-local, no barrier
        const float* f = sf + lane * NFEAT;
        const int   uid = (int)f[0];
        const int   iid = (int)f[1];
        const float age = f[2];
        const int   g   = (f[4] > 0.5f) ? 1 : 0;
        float oacc = 0.f, macc = 0.f;
        #pragma unroll
        for (int k = 1; k < 21; ++k) oacc += f[5 + k] * (float)k;
        #pragma unroll
        for (int j = 0; j < 19; ++j) macc += f[26 + j] * (float)(1u << j);
        const int      o = (int)oacc;
        const unsigned m = (unsigned)macc;
        unsigned aq = (unsigned)(age * 65536.0f);
        if (aq > 65535u) aq = 65535u;
        const unsigned lo = (unsigned)uid | ((unsigned)iid << 10) |
                            ((unsigned)o << 21) | ((unsigned)g << 26) |
                            ((m & 31u) << 27);
        const unsigned hi = (m >> 5) | (aq << 14);
        const int row = cb * 256 + wid * 64 + lane;
        reinterpret_cast<uint2*>(ws + OFF_CODE)[row] = make_uint2(lo, hi);
        return;
    }

    if (b == 405) {     // ---- consts ----
        float S = 0.f;
        for (int k = 0; k < 43; ++k) S += lin_w[k];
        const int i = tid;
        if (i == 0)       { ws[0] = S; ws[1] = lin_b[0]; ws[2] = lin_w[0]; }
        else if (i < 3)   { ws[OFF_LWG + i - 1] = lin_w[i]; }
        else if (i < 24)  { ws[OFF_LWO + i - 3] = lin_w[i]; }
        else if (i < 26)  { int g = i - 24; ws[OFF_AG + g] = S * dot64(AU, GU + g * 64); }
        else if (i < 47)  { int o = i - 26; ws[OFF_AO + o] = S * dot64(AU, OU + o * 64); }
        else if (i < 89)  { int j = i - 47; ws[OFF_GO + j] = S * dot64(GU + (j / 21) * 64, OU + (j % 21) * 64); }
        return;
    }

    // ---- GEMM modes (same math as R7) ----
    int mode, AR, BR, r0 = 0, c0 = 0;
    if (b < 405)                 { mode = 0; AR = 943;  BR = 1682; r0 = (b / 27) * 64; c0 = (b % 27) * 64; }
    else { b -= 406;
        if (b < 15)              { mode = 1; AR = 943;  BR = 28;  r0 = b * 64; }
        else if ((b -= 15) < 27) { mode = 2; AR = 1682; BR = 28;  r0 = b * 64; }
        else if ((b -= 27) < 15) { mode = 3; AR = 943;  BR = 19;  r0 = b * 64; }
        else if ((b -= 15) < 27) { mode = 4; AR = 1682; BR = 19;  r0 = b * 64; }
        else { b -= 27;            mode = 5; AR = 24;   BR = 256; c0 = b * 64; }
    }

    float S = 0.f;
    for (int k = 0; k < 43; ++k) S += lin_w[k];

    float* As = shbuf;            // [64][68] k-major
    float* Bs = shbuf + 4352;
    #pragma unroll
    for (int i = 0; i < 4; ++i) {
        const int q  = tid + i * 256;
        const int r  = q >> 4;
        const int c4 = (q & 15) * 4;
        float4 va = make_float4(0.f, 0.f, 0.f, 0.f);
        if (r0 + r < AR) {
            if (mode == 5) {
                const int rr = r0 + r;
                const float* srcp = (rr < 21) ? OI + rr * 64
                                  : (rr == 21) ? GI : (rr == 22) ? GI + 64 : AI;
                va = *reinterpret_cast<const float4*>(srcp + c4);
            } else {
                const float* Ap = (mode == 0) ? UI : (mode == 1) ? UU
                                : (mode == 2) ? TU : (mode == 3) ? UI : TI;
                va = *reinterpret_cast<const float4*>(Ap + (size_t)(r0 + r) * 64 + c4);
            }
        }
        As[(c4 + 0) * 68 + r] = va.x; As[(c4 + 1) * 68 + r] = va.y;
        As[(c4 + 2) * 68 + r] = va.z; As[(c4 + 3) * 68 + r] = va.w;
        float4 vb = make_float4(0.f, 0.f, 0.f, 0.f);
        const int cr = c0 + r;
        if (mode == 0) {
            if (cr < 1682) vb = *reinterpret_cast<const float4*>(TU + (size_t)cr * 64 + c4);
        } else if (mode == 1 || mode == 2) {
            const float* srcp = nullptr;
            if (mode == 1) srcp = (r < 21) ? OU + r * 64 : (r == 24) ? AU
                                 : (r == 25) ? GU : (r == 26) ? GU + 64 : nullptr;
            else           srcp = (r < 21) ? OI + r * 64 : (r == 24) ? AI
                                 : (r == 25) ? GI : (r == 26) ? GI + 64 : nullptr;
            if (srcp) vb = *reinterpret_cast<const float4*>(srcp + c4);
        } else if (mode == 3) {
            if (r < 19) vb = *reinterpret_cast<const float4*>(MU + r * 64 + c4);
        } else if (mode == 4) {
            if (r < 19) vb = *reinterpret_cast<const float4*>(MI + r * 64 + c4);
        } else {
            const int e = cr; int j0, L, s;
            if (e < 128)      { j0 = 0;  L = 7; s = e; }
            else if (e < 192) { j0 = 7;  L = 6; s = e - 128; }
            else              { j0 = 13; L = 6; s = e - 192; }
            for (int bb = 0; bb < L; ++bb) if ((s >> bb) & 1) {
                const float4 mu = *reinterpret_cast<const float4*>(MU + (j0 + bb) * 64 + c4);
                vb.x += mu.x; vb.y += mu.y; vb.z += mu.z; vb.w += mu.w;
            }
        }
        Bs[(c4 + 0) * 68 + r] = vb.x; Bs[(c4 + 1) * 68 + r] = vb.y;
        Bs[(c4 + 2) * 68 + r] = vb.z; Bs[(c4 + 3) * 68 + r] = vb.w;
    }
    __syncthreads();

    const int tx = tid & 15, ty = tid >> 4;
    float acc[4][4] = {};
    #pragma unroll 8
    for (int k = 0; k < 64; ++k) {
        const float4 a  = *reinterpret_cast<const float4*>(As + k * 68 + ty * 4);
        const float4 bv = *reinterpret_cast<const float4*>(Bs + k * 68 + tx * 4);
        const float av[4] = {a.x, a.y, a.z, a.w};
        const float bw[4] = {bv.x, bv.y, bv.z, bv.w};
        #pragma unroll
        for (int i = 0; i < 4; ++i)
            #pragma unroll
            for (int j = 0; j < 4; ++j)
                acc[i][j] += av[i] * bw[j];
    }

    if (mode == 0) {
        unsigned short* UTb = reinterpret_cast<unsigned short*>(ws + OFF_UTB);
        #pragma unroll
        for (int i = 0; i < 4; ++i) {
            const int gr = r0 + ty * 4 + i;
            if (gr >= 943) continue;
            #pragma unroll
            for (int jp = 0; jp < 2; ++jp) {
                const int gc = c0 + tx * 4 + jp * 2;
                if (gc >= 1682) continue;
                ushort2 st;
                st.x = f2b(S * acc[i][jp * 2]);
                st.y = f2b(S * acc[i][jp * 2 + 1]);
                *reinterpret_cast<ushort2*>(UTb + (size_t)gr * 1682 + gc) = st;
            }
        }
    } else if (mode == 1 || mode == 2) {
        unsigned short* Cb = reinterpret_cast<unsigned short*>(ws + (mode == 1 ? OFF_PUOB : OFF_PTOB));
        const float* wvec = (mode == 1) ? user_w : item_w;
        #pragma unroll
        for (int i = 0; i < 4; ++i) {
            const int gr = r0 + ty * 4 + i;
            if (gr >= AR) continue;
            #pragma unroll
            for (int j = 0; j < 4; ++j) {
                const int gc = tx * 4 + j;
                if (gc >= 28) continue;
                Cb[(size_t)gr * 32 + gc] = (gc == 27) ? f2b(wvec[gr]) : f2b(S * acc[i][j]);
            }
        }
    } else if (mode == 3 || mode == 4) {
        unsigned short* Cb = reinterpret_cast<unsigned short*>(ws + (mode == 3 ? OFF_DMUB : OFF_DMTB));
        #pragma unroll
        for (int i = 0; i < 4; ++i) {
            const int gr = r0 + ty * 4 + i;
            if (gr >= AR) continue;
            #pragma unroll
            for (int j = 0; j < 4; ++j) {
                const int gc = tx * 4 + j;
                if (gc >= 19) continue;
                Cb[(size_t)gr * 32 + gc] = f2b(S * acc[i][j]);
            }
        }
    } else {
        #pragma unroll
        for (int i = 0; i < 4; ++i) {
            const int gr = ty * 4 + i;
            if (gr >= 24) continue;
            #pragma unroll
            for (int j = 0; j < 4; ++j) {
                const int gc = c0 + tx * 4 + j;
                float v = S * acc[i][j];
                if (gr == 21 || gr == 22) {
                    const int e = gc; int j0, L, s;
                    if (e < 128)      { j0 = 0;  L = 7; s = e; }
                    else if (e < 192) { j0 = 7;  L = 6; s = e - 128; }
                    else              { j0 = 13; L = 6; s = e - 192; }
                    for (int bb = 0; bb < L; ++bb) if ((s >> bb) & 1) v += lin_w[24 + j0 + bb];
                }
                ws[OFF_NO + gr * 256 + gc] = v;
            }
        }
    }
}

// ================= F': pure-gather scoring =================
__global__ __launch_bounds__(256) void ffm_final(const float* __restrict__ ws,
                                                 float* __restrict__ out)
{
    __shared__ float T[LDS_TAB];
    const int tid = threadIdx.x;
    for (int i = tid; i < LDS_TAB; i += 256) T[i] = ws[i];
    __syncthreads();

    const int row = blockIdx.x * 256 + tid;
    const uint2 cd = reinterpret_cast<const uint2*>(ws + OFF_CODE)[row];
    const int uid = cd.x & 1023;
    const int iid = (cd.x >> 10) & 2047;
    const int o   = (cd.x >> 21) & 31;
    const int g   = (cd.x >> 26) & 1;
    const unsigned m = ((cd.x >> 27) & 31u) | ((cd.y & 0x3FFFu) << 5);
    const float age  = (float)((cd.y >> 14) & 0xFFFFu) * (1.0f / 65536.0f);
    const int c0 = m & 127, c1 = (m >> 7) & 63, c2 = m >> 13;

    const unsigned short* pu = reinterpret_cast<const unsigned short*>(ws + OFF_PUOB) + (size_t)uid * 32;
    const unsigned short* pt = reinterpret_cast<const unsigned short*>(ws + OFF_PTOB) + (size_t)iid * 32;
    const ushort4 qu = *reinterpret_cast<const ushort4*>(pu + 24);  // {au,gu0,gu1,w}
    const ushort4 qt = *reinterpret_cast<const ushort4*>(pt + 24);
    const float ouv = b2f(pu[o]);
    const float otv = b2f(pt[o]);

    const unsigned short* UTb = reinterpret_cast<const unsigned short*>(ws + OFF_UTB);
    const float utv = b2f(UTb[(size_t)uid * 1682 + iid]);

    const unsigned short* du = reinterpret_cast<const unsigned short*>(ws + OFF_DMUB) + (size_t)uid * 32;
    const unsigned short* dt = reinterpret_cast<const unsigned short*>(ws + OFF_DMTB) + (size_t)iid * 32;
    float mu_acc = 0.f, mt_acc = 0.f;
    unsigned mm = m;
    while (mm) {
        const int j = __builtin_ctz(mm);
        mm &= mm - 1;
        mu_acc += b2f(du[j]);
        mt_acc += b2f(dt[j]);
    }

    const float nov = T[OFF_NO + o * 256 + c0] + T[OFF_NO + o * 256 + 128 + c1] + T[OFF_NO + o * 256 + 192 + c2];
    const float nfv = T[OFF_NF + g * 256 + c0] + T[OFF_NF + g * 256 + 128 + c1] + T[OFF_NF + g * 256 + 192 + c2];
    const float nav = T[OFF_NA + c0] + T[OFF_NA + 128 + c1] + T[OFF_NA + 192 + c2];

    const float total =
          b2f(qu.w) + b2f(qt.w) + T[1]
        + age * T[2] + T[OFF_LWG + g] + T[OFF_LWO + o]
        + age * (T[OFF_AG + g] + T[OFF_AO + o] + b2f(qu.x) + b2f(qt.x))
        + (g ? b2f(qu.z) : b2f(qu.y)) + (g ? b2f(qt.z) : b2f(qt.y))
        + T[OFF_GO + g * 21 + o] + ouv + otv + utv
        + nfv + age * nav + nov + mu_acc + mt_acc;

    out[row] = 1.f / (1.f + __expf(-total));
}

// ---- fallback (round-2 kernel) if ws is too small ----
constexpr int RPW = 16, THREADS = 256, WPB = 4, FPW = RPW * NFEAT;
__global__ __launch_bounds__(THREADS) void ffm_fallback(
    const float* __restrict__ fv,
    const float* __restrict__ AU, const float* __restrict__ AI,
    const float* __restrict__ GU, const float* __restrict__ GI,
    const float* __restrict__ OU, const float* __restrict__ OI,
    const float* __restrict__ MU, const float* __restrict__ MI,
    const float* __restrict__ UU, const float* __restrict__ UI,
    const float* __restrict__ TU, const float* __restrict__ TI,
    const float* __restrict__ user_w, const float* __restrict__ item_w,
    const float* __restrict__ lin_w, const float* __restrict__ lin_b,
    float* __restrict__ out)
{
    __shared__ __align__(16) float stage[WPB][FPW];
    const int lane = threadIdx.x & 63;
    const int wid  = threadIdx.x >> 6;
    const int rowBase = (blockIdx.x * WPB + wid) * RPW;
    {
        const float* src = fv + (size_t)rowBase * NFEAT;
        float* dst = stage[wid];
        #pragma unroll
        for (int t = 0; t < 3; ++t) {
            const int idx = t * 64 + lane;
            if (idx < FPW / 4)
                *reinterpret_cast<float4*>(dst + idx * 4) =
                    *reinterpret_cast<const float4*>(src + idx * 4);
        }
    }
    const float* Srow = stage[wid];
    const float au_w = AU[lane], ai_w = AI[lane];
    const float gu0 = GU[lane], gu1 = GU[64 + lane];
    const float gi0 = GI[lane], gi1 = GI[64 + lane];
    const float lw = (lane >= 2 && lane < NFEAT) ? lin_w[lane - 2] : 0.0f;
    const float bias = lin_b[0];
    float sum_lin = lw;
    #pragma unroll
    for (int off = 32; off; off >>= 1) sum_lin += __shfl_xor(sum_lin, off);
    float myval = 0.0f;
    for (int r = 0; r < RPW; ++r) {
        const float* rp = Srow + r * NFEAT;
        const float x = (lane < NFEAT) ? rp[lane] : 0.0f;
        const int uid = (int)rp[0], iid = (int)rp[1];
        const float age = rp[2], g0 = rp[3], g1 = rp[4];
        const unsigned long long ball = __ballot(x != 0.0f);
        const unsigned occm = (unsigned)((ball >> 5) & 0x1FFFFFull);
        unsigned movm = (unsigned)((ball >> 26) & 0x7FFFFull);
        const float au = age * au_w, ai = age * ai_w;
        const float gu = g0 * gu0 + g1 * gu1, gi = g0 * gi0 + g1 * gi1;
        float ou = 0.0f, oi = 0.0f;
        if (occm) { const int j = __builtin_ctz(occm); ou = OU[j * 64 + lane]; oi = OI[j * 64 + lane]; }
        float mu = 0.0f, mi = 0.0f;
        while (movm) { const int j = __builtin_ctz(movm); movm &= movm - 1; mu += MU[j * 64 + lane]; mi += MI[j * 64 + lane]; }
        const float uu = UU[uid * 64 + lane], ui_ = UI[uid * 64 + lane];
        const float tu = TU[iid * 64 + lane], ti = TI[iid * 64 + lane];
        const float part = (ai + gi + oi) * (mu + tu) + au * (gu + ou + uu)
                         + gu * (ou + uu) + ou * uu + mu * ui_ + mi * ti + ui_ * tu;
        float red = part * sum_lin + x * lw;
        #pragma unroll
        for (int off = 32; off; off >>= 1) red += __shfl_xor(red, off);
        const float val = user_w[uid] + item_w[iid] + bias + red;
        if (lane == r) myval = val;
    }
    if (lane < RPW) out[rowBase + lane] = 1.0f / (1.0f + __expf(-myval));
}

extern "C" void kernel_launch(void* const* d_in, const int* in_sizes, int n_in,
                              void* d_out, int out_size, void* d_ws, size_t ws_size,
                              hipStream_t stream) {
    const float* fv = (const float*)d_in[0];
    const float* AU = (const float*)d_in[1];
    const float* AI = (const float*)d_in[2];
    const float* GU = (const float*)d_in[3];
    const float* GI = (const float*)d_in[4];
    const float* OU = (const float*)d_in[5];
    const float* OI = (const float*)d_in[6];
    const float* MU = (const float*)d_in[7];
    const float* MI = (const float*)d_in[8];
    const float* UU = (const float*)d_in[9];
    const float* UI = (const float*)d_in[10];
    const float* TU = (const float*)d_in[11];
    const float* TI = (const float*)d_in[12];
    const float* uw = (const float*)d_in[13];
    const float* iw = (const float*)d_in[14];
    const float* lw = (const float*)d_in[15];
    const float* lb = (const float*)d_in[16];
    float* out = (float*)d_out;
    float* ws  = (float*)d_ws;

    if (ws_size < TOT_BYTES) {
        ffm_fallback<<<B_ROWS / RPW / WPB, THREADS, 0, stream>>>(
            fv, AU, AI, GU, GI, OU, OI, MU, MI, UU, UI, TU, TI, uw, iw, lw, lb, out);
        return;
    }

    ka2_kernel<<<KA2_BLOCKS, 256, 0, stream>>>(
        fv, AU, AI, GU, GI, OU, OI, MU, MI, UU, UI, TU, TI, uw, iw, lw, lb, ws);
    // DIAGNOSTIC: ffm_final is idempotent; 4 launches => dur delta ≈ 3 * F_time
    ffm_final<<<B_ROWS / 256, 256, 0, stream>>>(ws, out);
    ffm_final<<<B_ROWS / 256, 256, 0, stream>>>(ws, out);
    ffm_final<<<B_ROWS / 256, 256, 0, stream>>>(ws, out);
    ffm_final<<<B_ROWS / 256, 256, 0, stream>>>(ws, out);
}

// Round 10
// 44.700 us; speedup vs baseline: 1.7427x; 1.7427x over previous
//
#include <hip/hip_runtime.h>
#include <math.h>

// FFM_69664369541798 — round 10: two plain dispatches (no cooperative launch —
// it hangs graph capture).
// KP (494 blk): UT/PUO/PTO/DMU/DMT/NOX GEMMs + consts  ->  ws tables
// F  (1024 blk): stage 256 fv rows in LDS, decode in-register, gather, score.

constexpr int B_ROWS = 262144;
constexpr int NFEAT  = 45;

// ---- ws layout (float-element offsets) ----
constexpr int OFF_LWG  = 8;        // 2
constexpr int OFF_LWO  = 10;       // 21
constexpr int OFF_AG   = 31;       // 2
constexpr int OFF_AO   = 33;       // 21
constexpr int OFF_GO   = 54;       // 42 -> 96
constexpr int OFF_NO   = 96;       // 21*256 f32 (stays in global/L2)
constexpr int OFF_NF   = 5472;     // 2*256
constexpr int OFF_NA   = 5984;     // 256
constexpr int OFF_PUOB = 6240;     // bf16 943*32  (one 64B line per uid)
constexpr int OFF_PTOB = 21328;    // bf16 1682*32
constexpr int OFF_DMUB = 48240;    // bf16 943*32
constexpr int OFF_DMTB = 63328;    // bf16 1682*32
constexpr int OFF_UTB  = 90240;    // bf16 943*1682
constexpr size_t TOT_FLOATS = 883304;
constexpr size_t TOT_BYTES  = TOT_FLOATS * 4;

__device__ inline float dot64(const float* __restrict__ a, const float* __restrict__ b) {
    float s = 0.f;
    #pragma unroll
    for (int k = 0; k < 64; k += 4) {
        const float4 av = *reinterpret_cast<const float4*>(a + k);
        const float4 bv = *reinterpret_cast<const float4*>(b + k);
        s += av.x * bv.x + av.y * bv.y + av.z * bv.z + av.w * bv.w;
    }
    return s;
}
__device__ inline unsigned short f2b(float x) {
    union { float f; unsigned u; } v; v.f = x;
    return (unsigned short)((v.u + 0x7FFFu + ((v.u >> 16) & 1u)) >> 16);
}
__device__ inline float b2f(unsigned short u) {
    union { unsigned u; float f; } v; v.u = (unsigned)u << 16; return v.f;
}

// ================= KP: precompute GEMMs + consts (494 blocks) =================
constexpr int KP_BLOCKS = 494;

__global__ __launch_bounds__(256) void kp_kernel(
    const float* __restrict__ AU, const float* __restrict__ AI,
    const float* __restrict__ GU, const float* __restrict__ GI,
    const float* __restrict__ OU, const float* __restrict__ OI,
    const float* __restrict__ MU, const float* __restrict__ MI,
    const float* __restrict__ UU, const float* __restrict__ UI,
    const float* __restrict__ TU, const float* __restrict__ TI,
    const float* __restrict__ user_w, const float* __restrict__ item_w,
    const float* __restrict__ lin_w, const float* __restrict__ lin_b,
    float* __restrict__ ws)
{
    __shared__ __align__(16) float As[64 * 68];
    __shared__ __align__(16) float Bs[64 * 68];
    const int tid = threadIdx.x;
    int b = blockIdx.x;

    if (b == 405) {     // ---- consts ----
        float S = 0.f;
        for (int k = 0; k < 43; ++k) S += lin_w[k];
        const int i = tid;
        if (i == 0)       { ws[0] = S; ws[1] = lin_b[0]; ws[2] = lin_w[0]; }
        else if (i < 3)   { ws[OFF_LWG + i - 1] = lin_w[i]; }
        else if (i < 24)  { ws[OFF_LWO + i - 3] = lin_w[i]; }
        else if (i < 26)  { int g = i - 24; ws[OFF_AG + g] = S * dot64(AU, GU + g * 64); }
        else if (i < 47)  { int o = i - 26; ws[OFF_AO + o] = S * dot64(AU, OU + o * 64); }
        else if (i < 89)  { int j = i - 47; ws[OFF_GO + j] = S * dot64(GU + (j / 21) * 64, OU + (j % 21) * 64); }
        return;
    }

    // modes: 0 UT | 1 PUO | 2 PTO | 3 DMU | 4 DMT | 5 NOX
    int mode, AR, BR, r0 = 0, c0 = 0;
    if (b < 405)                 { mode = 0; AR = 943;  BR = 1682; r0 = (b / 27) * 64; c0 = (b % 27) * 64; }
    else { b -= 406;
        if (b < 15)              { mode = 1; AR = 943;  BR = 28;  r0 = b * 64; }
        else if ((b -= 15) < 27) { mode = 2; AR = 1682; BR = 28;  r0 = b * 64; }
        else if ((b -= 27) < 15) { mode = 3; AR = 943;  BR = 19;  r0 = b * 64; }
        else if ((b -= 15) < 27) { mode = 4; AR = 1682; BR = 19;  r0 = b * 64; }
        else { b -= 27;            mode = 5; AR = 24;   BR = 256; c0 = b * 64; }
    }

    float S = 0.f;
    for (int k = 0; k < 43; ++k) S += lin_w[k];

    #pragma unroll
    for (int i = 0; i < 4; ++i) {
        const int q  = tid + i * 256;
        const int r  = q >> 4;
        const int c4 = (q & 15) * 4;
        float4 va = make_float4(0.f, 0.f, 0.f, 0.f);
        if (r0 + r < AR) {
            if (mode == 5) {
                const int rr = r0 + r;
                const float* srcp = (rr < 21) ? OI + rr * 64
                                  : (rr == 21) ? GI : (rr == 22) ? GI + 64 : AI;
                va = *reinterpret_cast<const float4*>(srcp + c4);
            } else {
                const float* Ap = (mode == 0) ? UI : (mode == 1) ? UU
                                : (mode == 2) ? TU : (mode == 3) ? UI : TI;
                va = *reinterpret_cast<const float4*>(Ap + (size_t)(r0 + r) * 64 + c4);
            }
        }
        As[(c4 + 0) * 68 + r] = va.x; As[(c4 + 1) * 68 + r] = va.y;
        As[(c4 + 2) * 68 + r] = va.z; As[(c4 + 3) * 68 + r] = va.w;
        float4 vb = make_float4(0.f, 0.f, 0.f, 0.f);
        const int cr = c0 + r;
        if (mode == 0) {
            if (cr < 1682) vb = *reinterpret_cast<const float4*>(TU + (size_t)cr * 64 + c4);
        } else if (mode == 1 || mode == 2) {
            const float* srcp = nullptr;
            if (mode == 1) srcp = (r < 21) ? OU + r * 64 : (r == 24) ? AU
                                 : (r == 25) ? GU : (r == 26) ? GU + 64 : nullptr;
            else           srcp = (r < 21) ? OI + r * 64 : (r == 24) ? AI
                                 : (r == 25) ? GI : (r == 26) ? GI + 64 : nullptr;
            if (srcp) vb = *reinterpret_cast<const float4*>(srcp + c4);
        } else if (mode == 3) {
            if (r < 19) vb = *reinterpret_cast<const float4*>(MU + r * 64 + c4);
        } else if (mode == 4) {
            if (r < 19) vb = *reinterpret_cast<const float4*>(MI + r * 64 + c4);
        } else {
            const int e = cr; int j0, L, s;
            if (e < 128)      { j0 = 0;  L = 7; s = e; }
            else if (e < 192) { j0 = 7;  L = 6; s = e - 128; }
            else              { j0 = 13; L = 6; s = e - 192; }
            for (int bb = 0; bb < L; ++bb) if ((s >> bb) & 1) {
                const float4 mu = *reinterpret_cast<const float4*>(MU + (j0 + bb) * 64 + c4);
                vb.x += mu.x; vb.y += mu.y; vb.z += mu.z; vb.w += mu.w;
            }
        }
        Bs[(c4 + 0) * 68 + r] = vb.x; Bs[(c4 + 1) * 68 + r] = vb.y;
        Bs[(c4 + 2) * 68 + r] = vb.z; Bs[(c4 + 3) * 68 + r] = vb.w;
    }
    __syncthreads();

    const int tx = tid & 15, ty = tid >> 4;
    float acc[4][4] = {};
    #pragma unroll 8
    for (int k = 0; k < 64; ++k) {
        const float4 a  = *reinterpret_cast<const float4*>(As + k * 68 + ty * 4);
        const float4 bv = *reinterpret_cast<const float4*>(Bs + k * 68 + tx * 4);
        const float av[4] = {a.x, a.y, a.z, a.w};
        const float bw[4] = {bv.x, bv.y, bv.z, bv.w};
        #pragma unroll
        for (int i = 0; i < 4; ++i)
            #pragma unroll
            for (int j = 0; j < 4; ++j)
                acc[i][j] += av[i] * bw[j];
    }

    if (mode == 0) {
        unsigned short* UTb = reinterpret_cast<unsigned short*>(ws + OFF_UTB);
        #pragma unroll
        for (int i = 0; i < 4; ++i) {
            const int gr = r0 + ty * 4 + i;
            if (gr >= 943) continue;
            #pragma unroll
            for (int jp = 0; jp < 2; ++jp) {
                const int gc = c0 + tx * 4 + jp * 2;
                if (gc >= 1682) continue;
                ushort2 st;
                st.x = f2b(S * acc[i][jp * 2]);
                st.y = f2b(S * acc[i][jp * 2 + 1]);
                *reinterpret_cast<ushort2*>(UTb + (size_t)gr * 1682 + gc) = st;
            }
        }
    } else if (mode == 1 || mode == 2) {
        unsigned short* Cb = reinterpret_cast<unsigned short*>(ws + (mode == 1 ? OFF_PUOB : OFF_PTOB));
        const float* wvec = (mode == 1) ? user_w : item_w;
        #pragma unroll
        for (int i = 0; i < 4; ++i) {
            const int gr = r0 + ty * 4 + i;
            if (gr >= AR) continue;
            #pragma unroll
            for (int j = 0; j < 4; ++j) {
                const int gc = tx * 4 + j;
                if (gc >= 28) continue;
                Cb[(size_t)gr * 32 + gc] = (gc == 27) ? f2b(wvec[gr]) : f2b(S * acc[i][j]);
            }
        }
    } else if (mode == 3 || mode == 4) {
        unsigned short* Cb = reinterpret_cast<unsigned short*>(ws + (mode == 3 ? OFF_DMUB : OFF_DMTB));
        #pragma unroll
        for (int i = 0; i < 4; ++i) {
            const int gr = r0 + ty * 4 + i;
            if (gr >= AR) continue;
            #pragma unroll
            for (int j = 0; j < 4; ++j) {
                const int gc = tx * 4 + j;
                if (gc >= 19) continue;
                Cb[(size_t)gr * 32 + gc] = f2b(S * acc[i][j]);
            }
        }
    } else {
        #pragma unroll
        for (int i = 0; i < 4; ++i) {
            const int gr = ty * 4 + i;
            if (gr >= 24) continue;
            #pragma unroll
            for (int j = 0; j < 4; ++j) {
                const int gc = c0 + tx * 4 + j;
                float v = S * acc[i][j];
                if (gr == 21 || gr == 22) {
                    const int e = gc; int j0, L, s;
                    if (e < 128)      { j0 = 0;  L = 7; s = e; }
                    else if (e < 192) { j0 = 7;  L = 6; s = e - 128; }
                    else              { j0 = 13; L = 6; s = e - 192; }
                    for (int bb = 0; bb < L; ++bb) if ((s >> bb) & 1) v += lin_w[24 + j0 + bb];
                }
                ws[OFF_NO + gr * 256 + gc] = v;
            }
        }
    }
}

// ================= F: fused stream+decode+gather+score =================
__global__ __launch_bounds__(256) void ffm_fused(const float* __restrict__ fv,
                                                 const float* __restrict__ ws,
                                                 float* __restrict__ out)
{
    __shared__ __align__(16) float sf[4][2880];   // 46 KB: 4 waves x 64 rows x 45
    __shared__ float T[864];                       // consts 96 | NF 512 | NA 256
    const int tid  = threadIdx.x;
    const int lane = tid & 63;
    const int wid  = tid >> 6;

    for (int i = tid; i < 96;  i += 256) T[i]       = ws[i];
    for (int i = tid; i < 512; i += 256) T[96 + i]  = ws[OFF_NF + i];
    for (int i = tid; i < 256; i += 256) T[608 + i] = ws[OFF_NA + i];

    const int row0 = blockIdx.x * 256;
    {
        const float* src = fv + (size_t)(row0 + wid * 64) * NFEAT;
        float* dst = sf[wid];
        #pragma unroll
        for (int i = 0; i < 11; ++i) {
            const int s4 = i * 64 + lane;
            *reinterpret_cast<float4*>(dst + s4 * 4) =
                *reinterpret_cast<const float4*>(src + s4 * 4);
        }
        dst[2816 + lane] = src[2816 + lane];
    }
    __syncthreads();   // T is block-shared; sf is wave-local but barrier covers both

    const float* f = sf[wid] + lane * NFEAT;
    const int   uid = (int)f[0];
    const int   iid = (int)f[1];
    const float age = f[2];
    const int   g   = (f[4] > 0.5f) ? 1 : 0;
    float oacc = 0.f, macc = 0.f;
    #pragma unroll
    for (int k = 1; k < 21; ++k) oacc += f[5 + k] * (float)k;
    #pragma unroll
    for (int j = 0; j < 19; ++j) macc += f[26 + j] * (float)(1u << j);
    const int      o = (int)oacc;
    const unsigned m = (unsigned)macc;
    const int c0 = m & 127, c1 = (m >> 7) & 63, c2 = m >> 13;

    const unsigned short* pu = reinterpret_cast<const unsigned short*>(ws + OFF_PUOB) + (size_t)uid * 32;
    const unsigned short* pt = reinterpret_cast<const unsigned short*>(ws + OFF_PTOB) + (size_t)iid * 32;
    const ushort4 qu = *reinterpret_cast<const ushort4*>(pu + 24);  // {au,gu0,gu1,w}
    const ushort4 qt = *reinterpret_cast<const ushort4*>(pt + 24);
    const float ouv = b2f(pu[o]);
    const float otv = b2f(pt[o]);

    const unsigned short* UTb = reinterpret_cast<const unsigned short*>(ws + OFF_UTB);
    const float utv = b2f(UTb[(size_t)uid * 1682 + iid]);

    const unsigned short* du = reinterpret_cast<const unsigned short*>(ws + OFF_DMUB) + (size_t)uid * 32;
    const unsigned short* dt = reinterpret_cast<const unsigned short*>(ws + OFF_DMTB) + (size_t)iid * 32;
    float mu_acc = 0.f, mt_acc = 0.f;
    unsigned mm = m;
    while (mm) {
        const int j = __builtin_ctz(mm);
        mm &= mm - 1;
        mu_acc += b2f(du[j]);
        mt_acc += b2f(dt[j]);
    }

    const float* no = ws + OFF_NO + o * 256;     // 21.5 KB table, L2-resident
    const float nov = no[c0] + no[128 + c1] + no[192 + c2];
    const float nfv = T[96 + g * 256 + c0] + T[96 + g * 256 + 128 + c1] + T[96 + g * 256 + 192 + c2];
    const float nav = T[608 + c0] + T[608 + 128 + c1] + T[608 + 192 + c2];

    const float total =
          b2f(qu.w) + b2f(qt.w) + T[1]
        + age * T[2] + T[OFF_LWG + g] + T[OFF_LWO + o]
        + age * (T[OFF_AG + g] + T[OFF_AO + o] + b2f(qu.x) + b2f(qt.x))
        + (g ? b2f(qu.z) : b2f(qu.y)) + (g ? b2f(qt.z) : b2f(qt.y))
        + T[OFF_GO + g * 21 + o] + ouv + otv + utv
        + nfv + age * nav + nov + mu_acc + mt_acc;

    out[row0 + wid * 64 + lane] = 1.f / (1.f + __expf(-total));
}

// ---- fallback (round-2 kernel) if ws is too small ----
constexpr int RPW = 16, THREADS = 256, WPB = 4, FPW = RPW * NFEAT;
__global__ __launch_bounds__(THREADS) void ffm_fallback(
    const float* __restrict__ fv,
    const float* __restrict__ AU, const float* __restrict__ AI,
    const float* __restrict__ GU, const float* __restrict__ GI,
    const float* __restrict__ OU, const float* __restrict__ OI,
    const float* __restrict__ MU, const float* __restrict__ MI,
    const float* __restrict__ UU, const float* __restrict__ UI,
    const float* __restrict__ TU, const float* __restrict__ TI,
    const float* __restrict__ user_w, const float* __restrict__ item_w,
    const float* __restrict__ lin_w, const float* __restrict__ lin_b,
    float* __restrict__ out)
{
    __shared__ __align__(16) float stage[WPB][FPW];
    const int lane = threadIdx.x & 63;
    const int wid  = threadIdx.x >> 6;
    const int rowBase = (blockIdx.x * WPB + wid) * RPW;
    {
        const float* src = fv + (size_t)rowBase * NFEAT;
        float* dst = stage[wid];
        #pragma unroll
        for (int t = 0; t < 3; ++t) {
            const int idx = t * 64 + lane;
            if (idx < FPW / 4)
                *reinterpret_cast<float4*>(dst + idx * 4) =
                    *reinterpret_cast<const float4*>(src + idx * 4);
        }
    }
    const float* Srow = stage[wid];
    const float au_w = AU[lane], ai_w = AI[lane];
    const float gu0 = GU[lane], gu1 = GU[64 + lane];
    const float gi0 = GI[lane], gi1 = GI[64 + lane];
    const float lw = (lane >= 2 && lane < NFEAT) ? lin_w[lane - 2] : 0.0f;
    const float bias = lin_b[0];
    float sum_lin = lw;
    #pragma unroll
    for (int off = 32; off; off >>= 1) sum_lin += __shfl_xor(sum_lin, off);
    float myval = 0.0f;
    for (int r = 0; r < RPW; ++r) {
        const float* rp = Srow + r * NFEAT;
        const float x = (lane < NFEAT) ? rp[lane] : 0.0f;
        const int uid = (int)rp[0], iid = (int)rp[1];
        const float age = rp[2], g0 = rp[3], g1 = rp[4];
        const unsigned long long ball = __ballot(x != 0.0f);
        const unsigned occm = (unsigned)((ball >> 5) & 0x1FFFFFull);
        unsigned movm = (unsigned)((ball >> 26) & 0x7FFFFull);
        const float au = age * au_w, ai = age * ai_w;
        const float gu = g0 * gu0 + g1 * gu1, gi = g0 * gi0 + g1 * gi1;
        float ou = 0.0f, oi = 0.0f;
        if (occm) { const int j = __builtin_ctz(occm); ou = OU[j * 64 + lane]; oi = OI[j * 64 + lane]; }
        float mu = 0.0f, mi = 0.0f;
        while (movm) { const int j = __builtin_ctz(movm); movm &= movm - 1; mu += MU[j * 64 + lane]; mi += MI[j * 64 + lane]; }
        const float uu = UU[uid * 64 + lane], ui_ = UI[uid * 64 + lane];
        const float tu = TU[iid * 64 + lane], ti = TI[iid * 64 + lane];
        const float part = (ai + gi + oi) * (mu + tu) + au * (gu + ou + uu)
                         + gu * (ou + uu) + ou * uu + mu * ui_ + mi * ti + ui_ * tu;
        float red = part * sum_lin + x * lw;
        #pragma unroll
        for (int off = 32; off; off >>= 1) red += __shfl_xor(red, off);
        const float val = user_w[uid] + item_w[iid] + bias + red;
        if (lane == r) myval = val;
    }
    if (lane < RPW) out[rowBase + lane] = 1.0f / (1.0f + __expf(-myval));
}

extern "C" void kernel_launch(void* const* d_in, const int* in_sizes, int n_in,
                              void* d_out, int out_size, void* d_ws, size_t ws_size,
                              hipStream_t stream) {
    const float* fv = (const float*)d_in[0];
    const float* AU = (const float*)d_in[1];
    const float* AI = (const float*)d_in[2];
    const float* GU = (const float*)d_in[3];
    const float* GI = (const float*)d_in[4];
    const float* OU = (const float*)d_in[5];
    const float* OI = (const float*)d_in[6];
    const float* MU = (const float*)d_in[7];
    const float* MI = (const float*)d_in[8];
    const float* UU = (const float*)d_in[9];
    const float* UI = (const float*)d_in[10];
    const float* TU = (const float*)d_in[11];
    const float* TI = (const float*)d_in[12];
    const float* uw = (const float*)d_in[13];
    const float* iw = (const float*)d_in[14];
    const float* lw = (const float*)d_in[15];
    const float* lb = (const float*)d_in[16];
    float* out = (float*)d_out;
    float* ws  = (float*)d_ws;

    if (ws_size < TOT_BYTES) {
        ffm_fallback<<<B_ROWS / RPW / WPB, THREADS, 0, stream>>>(
            fv, AU, AI, GU, GI, OU, OI, MU, MI, UU, UI, TU, TI, uw, iw, lw, lb, out);
        return;
    }

    kp_kernel<<<KP_BLOCKS, 256, 0, stream>>>(
        AU, AI, GU, GI, OU, OI, MU, MI, UU, UI, TU, TI, uw, iw, lw, lb, ws);
    ffm_fused<<<B_ROWS / 256, 256, 0, stream>>>(fv, ws, out);
}